// Round 14
// baseline (1017.966 us; speedup 1.0000x reference)
//
#include <hip/hip_runtime.h>
#include <hip/hip_bf16.h>

#define BATCH 32
#define NN 1024
#define MM 1024
#define KK 64
#define DD 2052                         // padded diag rows (staged up to 2048)
#define SCALE 14.4269504088896f         // 1/(gamma*ln2), gamma = 0.1
#define INV_SCALE 0.0693147180559945f   // gamma*ln2
#define BIGU 1.44269504e11f             // 1e10 * SCALE

typedef _Float16 h4 __attribute__((ext_vector_type(4)));
typedef float f4 __attribute__((ext_vector_type(4)));

// LDS-visibility barrier WITHOUT the __syncthreads() vmcnt(0) drain.
#define LDS_BARRIER() asm volatile("s_waitcnt lgkmcnt(0)\ns_barrier" ::: "memory")

// ---------------------------------------------------------------------------
// Kernel 1: pairwise sq-Euclidean distances, pre-scaled, f16. Unchanged
// (verified R5..R10).
// ---------------------------------------------------------------------------
template <int DIAG>
__global__ __launch_bounds__(256) void dist_kernel(
    const float* __restrict__ x, const float* __restrict__ y,
    _Float16* __restrict__ D) {
  const int b  = blockIdx.z;
  const int ti = blockIdx.y;
  const int tj = blockIdx.x;
  const int t  = threadIdx.x;

  __shared__ float xs[64][68];
  __shared__ float ys[64][68];

  {
    const int lr = t >> 4;
    const int lc = (t & 15) * 4;
    const float* xp = x + (size_t)(b * NN + ti * 64) * KK;
    const float* yp = y + (size_t)(b * MM + tj * 64) * KK;
#pragma unroll
    for (int r = 0; r < 4; ++r) {
      const int row = lr + r * 16;
      f4 xv = *(const f4*)(xp + (size_t)row * KK + lc);
      f4 yv = *(const f4*)(yp + (size_t)row * KK + lc);
      xs[row][lc + 0] = xv[0]; xs[row][lc + 1] = xv[1];
      xs[row][lc + 2] = xv[2]; xs[row][lc + 3] = xv[3];
      ys[row][lc + 0] = yv[0]; ys[row][lc + 1] = yv[1];
      ys[row][lc + 2] = yv[2]; ys[row][lc + 3] = yv[3];
    }
  }
  __syncthreads();

  const int tx = (t & 15) * 4;
  const int ty = (t >> 4) * 4;

  float acc[4][4];
  float x2[4], y2[4];
#pragma unroll
  for (int a = 0; a < 4; ++a) {
    x2[a] = 0.f; y2[a] = 0.f;
#pragma unroll
    for (int c = 0; c < 4; ++c) acc[a][c] = 0.f;
  }

#pragma unroll 4
  for (int k = 0; k < KK; k += 4) {
    f4 xa[4], yb[4];
#pragma unroll
    for (int a = 0; a < 4; ++a) xa[a] = *(const f4*)&xs[ty + a][k];
#pragma unroll
    for (int c = 0; c < 4; ++c) yb[c] = *(const f4*)&ys[tx + c][k];
#pragma unroll
    for (int a = 0; a < 4; ++a) {
      x2[a] += xa[a][0] * xa[a][0] + xa[a][1] * xa[a][1] +
               xa[a][2] * xa[a][2] + xa[a][3] * xa[a][3];
      y2[a] += yb[a][0] * yb[a][0] + yb[a][1] * yb[a][1] +
               yb[a][2] * yb[a][2] + yb[a][3] * yb[a][3];
    }
#pragma unroll
    for (int a = 0; a < 4; ++a)
#pragma unroll
      for (int c = 0; c < 4; ++c)
        acc[a][c] += xa[a][0] * yb[c][0] + xa[a][1] * yb[c][1] +
                     xa[a][2] * yb[c][2] + xa[a][3] * yb[c][3];
  }

  if constexpr (DIAG) {
    __shared__ _Float16 dbuf[127][66];
#pragma unroll
    for (int a = 0; a < 4; ++a)
#pragma unroll
      for (int c = 0; c < 4; ++c) {
        const int li = ty + a, lj = tx + c;
        dbuf[li + lj][li] =
            (_Float16)((x2[a] + y2[c] - 2.0f * acc[a][c]) * SCALE);
      }
    __syncthreads();

    _Float16* Db = D + (size_t)b * DD * NN;
    const int wave = t >> 6, lane = t & 63;
    const int d0 = ti * 64 + tj * 64;
    const int c0 = ti * 64;
    for (int ld = wave; ld < 127; ld += 4) {
      const int lo = ld > 63 ? ld - 63 : 0;
      const int hi = ld < 63 ? ld : 63;
      const int li = lo + lane;
      if (li <= hi)
        Db[(size_t)(d0 + ld) * NN + c0 + li] = dbuf[ld][li];
    }
  } else {
    _Float16* Dp = D + (size_t)b * NN * MM + (size_t)(ti * 64 + ty) * MM +
                   (tj * 64 + tx);
#pragma unroll
    for (int a = 0; a < 4; ++a) {
      h4 v;
#pragma unroll
      for (int c = 0; c < 4; ++c)
        v[c] = (_Float16)((x2[a] + y2[c] - 2.0f * acc[a][c]) * SCALE);
      *(h4*)(Dp + (size_t)a * MM) = v;
    }
  }
}

// ---------------------------------------------------------------------------
// Kernel 2 (diag layout), C=8: EIGHT diagonals per barrier.
// Thread t owns rows i0..i0+3 (i0=4t) with an 8-row halo -> state w1/w2[12],
// w[j] = row i0-8+j. Exchange reads TWO neighbors (t-1 -> slots 4..7,
// t-2 -> slots 0..3), SoA conflict-free. Per round: 8-step staircase,
// step c computes diag d0+c-1 for J=c..11 (60 cells). D double-banked as
// h4 G[3][8] (G[J>>2][q] = rows segment, q = diag-in-block), static indices.
// ---------------------------------------------------------------------------
__global__ __launch_bounds__(256) void dtw_diag_kernel(
    const _Float16* __restrict__ Dd, float* __restrict__ out) {
  const int b  = blockIdx.x;
  const int t  = threadIdx.x;
  const int i0 = t * 4;
  const _Float16* Db = Dd + (size_t)b * DD * NN;

  __shared__ float lex[2][8][256];   // [parity][slot][thread] — SoA, conflict-free

  float w1[12], w2[12];
#pragma unroll
  for (int j = 0; j < 12; ++j) { w1[j] = BIGU; w2[j] = BIGU; }
  if (t == 0) w1[8] = (float)Db[0];   // row 0 (J=8), diag 0

  h4 GA[3][8], GB[3][8];

#define STAGE(G, D0S)                                                         \
  do {                                                                        \
    const long long _o = (long long)(D0S) * NN;                               \
    _Pragma("unroll")                                                         \
    for (int _q = 0; _q < 8; ++_q) {                                          \
      G[0][_q] = *(const h4*)(Db + (size_t)(_o + _q * NN + i0 - 8));          \
      G[1][_q] = *(const h4*)(Db + (size_t)(_o + _q * NN + i0 - 4));          \
      G[2][_q] = *(const h4*)(Db + (size_t)(_o + _q * NN + i0));              \
    }                                                                         \
  } while (0)

#define EXCHANGE(PAR)                                                         \
  do {                                                                        \
    lex[PAR][0][t] = w1[8];  lex[PAR][1][t] = w1[9];                          \
    lex[PAR][2][t] = w1[10]; lex[PAR][3][t] = w1[11];                         \
    lex[PAR][4][t] = w2[8];  lex[PAR][5][t] = w2[9];                          \
    lex[PAR][6][t] = w2[10]; lex[PAR][7][t] = w2[11];                         \
    LDS_BARRIER();                                                            \
    if (t >= 2) {                                                             \
      w1[0] = lex[PAR][0][t - 2]; w1[1] = lex[PAR][1][t - 2];                 \
      w1[2] = lex[PAR][2][t - 2]; w1[3] = lex[PAR][3][t - 2];                 \
      w2[0] = lex[PAR][4][t - 2]; w2[1] = lex[PAR][5][t - 2];                 \
      w2[2] = lex[PAR][6][t - 2]; w2[3] = lex[PAR][7][t - 2];                 \
    } else {                                                                  \
      w1[0] = w1[1] = w1[2] = w1[3] = BIGU;                                   \
      w2[0] = w2[1] = w2[2] = w2[3] = BIGU;                                   \
    }                                                                         \
    if (t >= 1) {                                                             \
      w1[4] = lex[PAR][0][t - 1]; w1[5] = lex[PAR][1][t - 1];                 \
      w1[6] = lex[PAR][2][t - 1]; w1[7] = lex[PAR][3][t - 1];                 \
      w2[4] = lex[PAR][4][t - 1]; w2[5] = lex[PAR][5][t - 1];                 \
      w2[6] = lex[PAR][6][t - 1]; w2[7] = lex[PAR][7][t - 1];                 \
    } else {                                                                  \
      w1[4] = w1[5] = w1[6] = w1[7] = BIGU;                                   \
      w2[4] = w2[5] = w2[6] = w2[7] = BIGU;                                   \
    }                                                                         \
  } while (0)

  // One DP cell, in-place (descending J within a step keeps J-1 old).
#define CELL(J, DV, DG)                                                       \
  do {                                                                        \
    const int _ri = i0 - 8 + (J);                                             \
    const bool _v =                                                           \
        ((unsigned)_ri < (unsigned)NN) && ((unsigned)((DG)-_ri) < (unsigned)MM); \
    const float _a = w2[(J)-1], _b = w1[(J)-1], _c = w1[(J)];                 \
    const float _mn = fminf(fminf(_a, _b), _c);                               \
    const float _md = __builtin_amdgcn_fmed3f(_a, _b, _c);                    \
    const float _mx = fmaxf(fmaxf(_a, _b), _c);                               \
    const float _s = 1.0f + __builtin_amdgcn_exp2f(_mn - _md) +               \
                     __builtin_amdgcn_exp2f(_mn - _mx);                       \
    w2[(J)] = w1[(J)];                                                        \
    w1[(J)] = _v ? (float)(DV) + _mn - __builtin_amdgcn_logf(_s) : BIGU;      \
  } while (0)

#define CG(G, Q, J, DG) CELL(J, G[(J) >> 2][Q][(J)&3], DG)

#define STEP(G, Q, JMIN, DG)                                                  \
  do {                                                                        \
    if (11 >= (JMIN)) CG(G, Q, 11, DG);                                       \
    if (10 >= (JMIN)) CG(G, Q, 10, DG);                                       \
    if (9 >= (JMIN))  CG(G, Q, 9, DG);                                        \
    if (8 >= (JMIN))  CG(G, Q, 8, DG);                                        \
    if (7 >= (JMIN))  CG(G, Q, 7, DG);                                        \
    if (6 >= (JMIN))  CG(G, Q, 6, DG);                                        \
    if (5 >= (JMIN))  CG(G, Q, 5, DG);                                        \
    if (4 >= (JMIN))  CG(G, Q, 4, DG);                                        \
    if (3 >= (JMIN))  CG(G, Q, 3, DG);                                        \
    if (2 >= (JMIN))  CG(G, Q, 2, DG);                                        \
    if (1 >= (JMIN))  CG(G, Q, 1, DG);                                        \
  } while (0)

#define BLOCK8(PAR, G, D0V)                                                   \
  do {                                                                        \
    EXCHANGE(PAR);                                                            \
    STEP(G, 0, 1, (D0V));                                                     \
    STEP(G, 1, 2, (D0V) + 1);                                                 \
    STEP(G, 2, 3, (D0V) + 2);                                                 \
    STEP(G, 3, 4, (D0V) + 3);                                                 \
    STEP(G, 4, 5, (D0V) + 4);                                                 \
    STEP(G, 5, 6, (D0V) + 5);                                                 \
    STEP(G, 6, 7, (D0V) + 6);                                                 \
    STEP(G, 7, 8, (D0V) + 7);                                                 \
  } while (0)

  STAGE(GA, 1);   // diags 1..8
  STAGE(GB, 9);   // diags 9..16

  int d0 = 1;
  for (int n = 0; n < 127; ++n) {   // blocks: diags 1..2032
    BLOCK8(0, GA, d0);
    STAGE(GA, d0 + 16);
    BLOCK8(1, GB, d0 + 8);
    STAGE(GB, d0 + 24);
    d0 += 16;
  }
  // d0 == 2033. Final full block: diags 2033..2040 (bank A, staged @2033).
  BLOCK8(0, GA, 2033);

  // Peel diags 2041..2046 (bank B staged @2041; steps c=1..6).
  EXCHANGE(1);
  STEP(GB, 0, 1, 2041);
  STEP(GB, 1, 2, 2042);
  STEP(GB, 2, 3, 2043);
  STEP(GB, 3, 4, 2044);
  STEP(GB, 4, 5, 2045);
  STEP(GB, 5, 6, 2046);

  if (t == 255) out[b] = w1[11] * INV_SCALE;   // row 1023, diag 2046

#undef STAGE
#undef EXCHANGE
#undef CELL
#undef CG
#undef STEP
#undef BLOCK8
}

// ---------------------------------------------------------------------------
// Kernel 2 (row-major fallback): unchanged verified version.
// ---------------------------------------------------------------------------
__global__ __launch_bounds__(256) void dtw_row_kernel(
    const _Float16* __restrict__ D, float* __restrict__ out) {
  const int b  = blockIdx.x;
  const int t  = threadIdx.x;
  const int i0 = t * 4;
  const _Float16* Dr = D + (size_t)(b * NN + i0) * MM;

  __shared__ float lx[2][256];

  float r1[4], r2[4];
#pragma unroll
  for (int k = 0; k < 4; ++k) { r1[k] = BIGU; r2[k] = BIGU; }
  if (t == 0) r1[0] = (float)Dr[0];

  float dv[4], dvn[4];
#pragma unroll
  for (int k = 0; k < 4; ++k) {
    int j1 = 1 - (i0 + k);
    int jc1 = j1 < 0 ? 0 : (j1 > MM - 1 ? MM - 1 : j1);
    dv[k] = (float)Dr[(size_t)k * MM + jc1];
    int j2 = 2 - (i0 + k);
    int jc2 = j2 < 0 ? 0 : (j2 > MM - 1 ? MM - 1 : j2);
    dvn[k] = (float)Dr[(size_t)k * MM + jc2];
  }

  float nl1_prev = BIGU;

  for (int d = 1; d <= NN + MM - 2; ++d) {
    const int pp = d & 1;
    lx[pp][t] = r1[3];
    __syncthreads();
    const float nl1 = (t > 0) ? lx[pp][t - 1] : BIGU;
    const float nl2 = nl1_prev;

    float rn[4];
#pragma unroll
    for (int k = 0; k < 4; ++k) {
      const int j = d - (i0 + k);
      const float a  = k ? r2[k - 1] : nl2;
      const float bb = k ? r1[k - 1] : nl1;
      const float c  = r1[k];
      const float m  = fminf(fminf(a, bb), c);
      const float s  = exp2f(m - a) + exp2f(m - bb) + exp2f(m - c);
      const float sm = m - log2f(s);
      rn[k] = (j >= 0 && j < MM) ? dv[k] + sm : BIGU;
    }

    nl1_prev = nl1;
#pragma unroll
    for (int k = 0; k < 4; ++k) { r2[k] = r1[k]; r1[k] = rn[k]; dv[k] = dvn[k]; }

    const int dn = d + 2;
#pragma unroll
    for (int k = 0; k < 4; ++k) {
      int j = dn - (i0 + k);
      int jc = j < 0 ? 0 : (j > MM - 1 ? MM - 1 : j);
      dvn[k] = (float)Dr[(size_t)k * MM + jc];
    }
  }

  if (t == 255) out[b] = r1[3] * INV_SCALE;
}

// ---------------------------------------------------------------------------
extern "C" void kernel_launch(void* const* d_in, const int* in_sizes, int n_in,
                              void* d_out, int out_size, void* d_ws,
                              size_t ws_size, hipStream_t stream) {
  const float* x = (const float*)d_in[0];
  const float* y = (const float*)d_in[1];
  float* out = (float*)d_out;

  const size_t need_diag = (size_t)BATCH * DD * NN * sizeof(_Float16);  // ~134.5 MiB
  const size_t need_row  = (size_t)BATCH * NN * MM * sizeof(_Float16);  //   64  MiB
  dim3 g1(MM / 64, NN / 64, BATCH);

  if (ws_size >= need_diag) {
    _Float16* Dd = (_Float16*)d_ws;
    dist_kernel<1><<<g1, 256, 0, stream>>>(x, y, Dd);
    dtw_diag_kernel<<<BATCH, 256, 0, stream>>>(Dd, out);
  } else if (ws_size >= need_row) {
    _Float16* D = (_Float16*)d_ws;
    dist_kernel<0><<<g1, 256, 0, stream>>>(x, y, D);
    dtw_row_kernel<<<BATCH, 256, 0, stream>>>(D, out);
  }
  // else: workspace too small — fail visibly (output stays zero)
}